// Round 5
// baseline (401.828 us; speedup 1.0000x reference)
//
#include <hip/hip_runtime.h>
#include <hip/hip_bf16.h>

typedef __attribute__((ext_vector_type(8))) short v8s;   // 8 x bf16 (4 VGPRs)
typedef __attribute__((ext_vector_type(4))) float v4f;   // float4 / MFMA acc

constexpr int H  = 256;   // hidden channels
constexpr int K2 = 512;   // 2H = GEMM K
constexpr int BM = 64;    // edges per block
constexpr int BK = 64;    // K-tile
constexpr int XS = 72;    // padded LDS stride (bf16 elems) for X tile
constexpr int WS = 72;    // padded LDS stride for W1T tile

__device__ inline unsigned short f2bf(float f) {         // fp32 -> bf16 bits, RNE
    unsigned int u = __builtin_bit_cast(unsigned int, f);
    u += 0x7FFFu + ((u >> 16) & 1u);
    return (unsigned short)(u >> 16);
}

// ---- pre-kernel: W1 fp32 [512][256] (k-major) -> W1T bf16 [256][512] (n-major) ----
__global__ void w1_transpose_kernel(const float* __restrict__ w1,
                                    unsigned short* __restrict__ w1t) {
    __shared__ float tile[32][33];
    const int bk = blockIdx.x;            // 16 blocks over k
    const int bn = blockIdx.y;            // 8 blocks over n
    const int tx = threadIdx.x & 31;
    const int ty8 = threadIdx.x >> 5;     // 0..7
#pragma unroll
    for (int i = 0; i < 4; ++i) {
        int ty = i * 8 + ty8;
        tile[ty][tx] = w1[(size_t)(bk * 32 + ty) * H + bn * 32 + tx];   // coalesced read
    }
    __syncthreads();
#pragma unroll
    for (int i = 0; i < 4; ++i) {
        int ty = i * 8 + ty8;
        w1t[(size_t)(bn * 32 + ty) * K2 + bk * 32 + tx] = f2bf(tile[tx][ty]);
    }
}

// ---- main fused kernel: gather(fp32) + cast + GEMM(relu) + dot(W2) -> fp32 ----
__global__ __launch_bounds__(512, 4) void edge_decoder_kernel(
    const float* __restrict__ user_emb,     // [n_users][256] fp32
    const float* __restrict__ movie_emb,    // [n_movies][256] fp32
    const int* __restrict__ eli,            // [2][E] int32 (harness converts int64)
    const unsigned short* __restrict__ w1t, // [256][512] bf16 bits
    const float* __restrict__ b1,           // [256]
    const float* __restrict__ w2,           // [256]
    const float* __restrict__ b2,           // [1]
    float* __restrict__ out,                // [E]
    const int E, const int n_users, const int n_movies)
{
    __shared__ unsigned short Xs[BM * XS];  //  9216 B : 64 edges x 64 k (padded)
    __shared__ unsigned short Wts[H * WS];  // 36864 B : 256 n x 64 k (padded)
    __shared__ float red[4][BM];            //  1024 B : cross-wave partial sums

    const int t    = threadIdx.x;
    const int wave = t >> 6;
    const int lane = t & 63;
    const int wm   = wave >> 2;   // 0..1 : which 32-edge half
    const int wn   = wave & 3;    // 0..3 : which 64-col slice
    const int quad = lane >> 4;   // 0..3
    const int l16  = lane & 15;

    const long e0 = (long)blockIdx.x * BM;

    // --- X staging: row xr = t>>3 (0..63), k-chunk xc = t&7 -> floats [xc*8, xc*8+8) ---
    // (64 rows x 8 chunks of 8 floats = full 64x64 tile; 1 chunk per thread per K-tile)
    const int xr = t >> 3;
    const int xc = t & 7;
    long eg = e0 + xr;
    if (eg >= E) eg = 0;          // clamp tail rows (values unused)
    int iu = eli[eg];
    int im = eli[(long)E + eg];
    iu = iu < 0 ? 0 : (iu >= n_users  ? n_users  - 1 : iu);
    im = im < 0 ? 0 : (im >= n_movies ? n_movies - 1 : im);
    const float* urow = user_emb  + (size_t)iu * H;
    const float* mrow = movie_emb + (size_t)im * H;

    // --- W staging: rows j*64 + (t>>3) for j=0..3, 8-elem chunk t&7 (full 256x64) ---
    const int wr  = t >> 3;       // 0..63
    const int wc8 = t & 7;        // 0..7

    v4f acc[2][4];
#pragma unroll
    for (int mt = 0; mt < 2; ++mt)
#pragma unroll
        for (int nt = 0; nt < 4; ++nt)
            acc[mt][nt] = (v4f){0.f, 0.f, 0.f, 0.f};

    // register-prefetch X K-tile 0 (the gather is the long-latency access): 8 floats
    v4f xq0 = *(const v4f*)(urow + xc * 8);
    v4f xq1 = *(const v4f*)(urow + xc * 8 + 4);

    for (int kt = 0; kt < 8; ++kt) {
        __syncthreads();                              // prior compute done with LDS
        // X tile: cast prefetched fp32 -> bf16, store 16B to LDS
        {
            v8s xv;
#pragma unroll
            for (int i = 0; i < 4; ++i) xv[i]     = (short)f2bf(xq0[i]);
#pragma unroll
            for (int i = 0; i < 4; ++i) xv[4 + i] = (short)f2bf(xq1[i]);
            *(v8s*)(Xs + xr * XS + xc * 8) = xv;
        }
        // prefetch next X tile (hides under W staging + MFMA)
        if (kt < 7) {
            const int kn   = kt + 1;
            const int koff = (kn * BK) & 255;
            const float* src = ((kn < 4) ? urow : mrow) + koff + xc * 8;
            xq0 = *(const v4f*)(src);
            xq1 = *(const v4f*)(src + 4);
        }
        // W tile: global bf16 (L2-resident) -> LDS
        {
            v8s wv[4];
#pragma unroll
            for (int j = 0; j < 4; ++j)
                wv[j] = *(const v8s*)(w1t + (size_t)(j * 64 + wr) * K2 + kt * BK + wc8 * 8);
#pragma unroll
            for (int j = 0; j < 4; ++j)
                *(v8s*)(Wts + (j * 64 + wr) * WS + wc8 * 8) = wv[j];
        }
        __syncthreads();                              // tiles visible
#pragma unroll
        for (int ks = 0; ks < 2; ++ks) {
            v8s af[2], bf[4];
#pragma unroll
            for (int mt = 0; mt < 2; ++mt)            // A[m=l16][k=quad*8+j]
                af[mt] = *(const v8s*)(Xs + (wm * 32 + mt * 16 + l16) * XS + ks * 32 + quad * 8);
#pragma unroll
            for (int nt = 0; nt < 4; ++nt)            // B[k=quad*8+j][n=l16]
                bf[nt] = *(const v8s*)(Wts + (wn * 64 + nt * 16 + l16) * WS + ks * 32 + quad * 8);
#pragma unroll
            for (int mt = 0; mt < 2; ++mt)
#pragma unroll
                for (int nt = 0; nt < 4; ++nt)
                    acc[mt][nt] = __builtin_amdgcn_mfma_f32_16x16x32_bf16(
                        af[mt], bf[nt], acc[mt][nt], 0, 0, 0);
        }
    }

    // ---- epilogue: relu(acc + b1) * w2, reduce over n ----
    float b1v[4], w2v[4];
#pragma unroll
    for (int nt = 0; nt < 4; ++nt) {
        int n = wn * 64 + nt * 16 + l16;
        b1v[nt] = b1[n];
        w2v[nt] = w2[n];
    }
    const float b2v = b2[0];

#pragma unroll
    for (int mt = 0; mt < 2; ++mt) {
        float s[4] = {0.f, 0.f, 0.f, 0.f};
#pragma unroll
        for (int nt = 0; nt < 4; ++nt) {
#pragma unroll
            for (int j = 0; j < 4; ++j) {
                float h = acc[mt][nt][j] + b1v[nt];   // D row = quad*4+j, col = l16
                h = h > 0.f ? h : 0.f;
                s[j] += h * w2v[nt];
            }
        }
#pragma unroll
        for (int j = 0; j < 4; ++j) {
            float v = s[j];
            v += __shfl_xor(v, 1, 64);                // reduce 16 cols within quad
            v += __shfl_xor(v, 2, 64);
            v += __shfl_xor(v, 4, 64);
            v += __shfl_xor(v, 8, 64);
            if (l16 == 0)
                red[wn][wm * 32 + mt * 16 + quad * 4 + j] = v;
        }
    }
    __syncthreads();
    if (t < BM) {
        long e = e0 + t;
        if (e < E) {
            float v = red[0][t] + red[1][t] + red[2][t] + red[3][t] + b2v;
            out[e] = v;
        }
    }
}

extern "C" void kernel_launch(void* const* d_in, const int* in_sizes, int n_in,
                              void* d_out, int out_size, void* d_ws, size_t ws_size,
                              hipStream_t stream) {
    const float* user_emb  = (const float*)d_in[0];
    const float* movie_emb = (const float*)d_in[1];
    const int*   eli       = (const int*)d_in[2];
    const float* w1        = (const float*)d_in[3];
    const float* b1        = (const float*)d_in[4];
    const float* w2        = (const float*)d_in[5];
    const float* b2        = (const float*)d_in[6];
    float*       out       = (float*)d_out;

    const int E        = out_size;
    const int n_users  = in_sizes[0] / H;
    const int n_movies = in_sizes[1] / H;

    unsigned short* w1t = (unsigned short*)d_ws;      // 512*256*2 = 256 KiB scratch

    w1_transpose_kernel<<<dim3(16, 8), 256, 0, stream>>>(w1, w1t);
    const int nblocks = (E + BM - 1) / BM;
    edge_decoder_kernel<<<nblocks, 512, 0, stream>>>(
        user_emb, movie_emb, eli, w1t, b1, w2, b2, out, E, n_users, n_movies);
}

// Round 6
// 381.797 us; speedup vs baseline: 1.0525x; 1.0525x over previous
//
#include <hip/hip_runtime.h>
#include <hip/hip_bf16.h>

typedef __attribute__((ext_vector_type(8))) short v8s;   // 8 x bf16 (4 VGPRs)
typedef __attribute__((ext_vector_type(4))) float v4f;   // float4 / MFMA acc

constexpr int H  = 256;   // hidden channels
constexpr int K2 = 512;   // 2H = GEMM K
constexpr int BM = 64;    // edges per block
constexpr int BK = 64;    // K-tile
constexpr int XS = 72;    // padded LDS stride (bf16 elems) for X tile
constexpr int WS = 72;    // padded LDS stride for W1T tile

__device__ inline unsigned short f2bf(float f) {         // fp32 -> bf16 bits, RNE
    unsigned int u = __builtin_bit_cast(unsigned int, f);
    u += 0x7FFFu + ((u >> 16) & 1u);
    return (unsigned short)(u >> 16);
}

// ---- pre-kernel: W1 fp32 [512][256] (k-major) -> W1T bf16 [256][512] (n-major) ----
__global__ void w1_transpose_kernel(const float* __restrict__ w1,
                                    unsigned short* __restrict__ w1t) {
    __shared__ float tile[32][33];
    const int bk = blockIdx.x;            // 16 blocks over k
    const int bn = blockIdx.y;            // 8 blocks over n
    const int tx = threadIdx.x & 31;
    const int ty8 = threadIdx.x >> 5;     // 0..7
#pragma unroll
    for (int i = 0; i < 4; ++i) {
        int ty = i * 8 + ty8;
        tile[ty][tx] = w1[(size_t)(bk * 32 + ty) * H + bn * 32 + tx];   // coalesced read
    }
    __syncthreads();
#pragma unroll
    for (int i = 0; i < 4; ++i) {
        int ty = i * 8 + ty8;
        w1t[(size_t)(bn * 32 + ty) * K2 + bk * 32 + tx] = f2bf(tile[tx][ty]);
    }
}

// ---- main fused kernel: gather(fp32) + cast + GEMM(relu) + dot(W2) -> fp32 ----
__global__ __launch_bounds__(512, 4) void edge_decoder_kernel(
    const float* __restrict__ user_emb,     // [n_users][256] fp32
    const float* __restrict__ movie_emb,    // [n_movies][256] fp32
    const int* __restrict__ eli,            // [2][E] int32 (harness converts int64)
    const unsigned short* __restrict__ w1t, // [256][512] bf16 bits
    const float* __restrict__ b1,           // [256]
    const float* __restrict__ w2,           // [256]
    const float* __restrict__ b2,           // [1]
    float* __restrict__ out,                // [E]
    const int E, const int n_users, const int n_movies)
{
    __shared__ unsigned short Xs[BM * XS];  //  9216 B : 64 edges x 64 k (padded)
    __shared__ unsigned short Wts[H * WS];  // 36864 B : 256 n x 64 k (padded)
    __shared__ float red[4][BM];            //  1024 B : cross-wave partial sums

    const int t    = threadIdx.x;
    const int wave = t >> 6;
    const int lane = t & 63;
    const int wm   = wave >> 2;   // 0..1 : which 32-edge half
    const int wn   = wave & 3;    // 0..3 : which 64-col slice
    const int quad = lane >> 4;   // 0..3
    const int l16  = lane & 15;

    const long e0 = (long)blockIdx.x * BM;

    // --- X staging: row xr = t>>3 (0..63), k-chunk xc = t&7 -> floats [xc*8, xc*8+8) ---
    const int xr = t >> 3;
    const int xc = t & 7;
    long eg = e0 + xr;
    if (eg >= E) eg = 0;          // clamp tail rows (values unused)
    int iu = eli[eg];
    int im = eli[(long)E + eg];
    iu = iu < 0 ? 0 : (iu >= n_users  ? n_users  - 1 : iu);
    im = im < 0 ? 0 : (im >= n_movies ? n_movies - 1 : im);
    const float* urow = user_emb  + (size_t)iu * H;
    const float* mrow = movie_emb + (size_t)im * H;

    // --- W staging: rows j*64 + (t>>3) for j=0..3, 8-elem chunk t&7 (full 256x64) ---
    const int wr  = t >> 3;       // 0..63
    const int wc8 = t & 7;        // 0..7
    const unsigned short* wbase = w1t + (size_t)wr * K2 + wc8 * 8;   // + j*64*K2 + kt*BK

    v4f acc[2][4];
#pragma unroll
    for (int mt = 0; mt < 2; ++mt)
#pragma unroll
        for (int nt = 0; nt < 4; ++nt)
            acc[mt][nt] = (v4f){0.f, 0.f, 0.f, 0.f};

    // register-prefetch K-tile 0: X gather (HBM latency) first, then W (L2)
    v4f xq0 = *(const v4f*)(urow + xc * 8);
    v4f xq1 = *(const v4f*)(urow + xc * 8 + 4);
    v8s wq[4];
#pragma unroll
    for (int j = 0; j < 4; ++j)
        wq[j] = *(const v8s*)(wbase + (size_t)j * 64 * K2);

    for (int kt = 0; kt < 8; ++kt) {
        __syncthreads();                              // prior MFMA done reading LDS
        // X tile: cast prefetched fp32 -> bf16, 16B store to LDS
        {
            v8s xv;
#pragma unroll
            for (int i = 0; i < 4; ++i) xv[i]     = (short)f2bf(xq0[i]);
#pragma unroll
            for (int i = 0; i < 4; ++i) xv[4 + i] = (short)f2bf(xq1[i]);
            *(v8s*)(Xs + xr * XS + xc * 8) = xv;
        }
        // W tile: store prefetched regs to LDS
#pragma unroll
        for (int j = 0; j < 4; ++j)
            *(v8s*)(Wts + (j * 64 + wr) * WS + wc8 * 8) = wq[j];
        // issue next tile's loads now — latency overlaps MFMA phase below
        if (kt < 7) {
            const int kn   = kt + 1;
            const int koff = (kn * BK) & 255;
            const float* src = ((kn < 4) ? urow : mrow) + koff + xc * 8;
            xq0 = *(const v4f*)(src);
            xq1 = *(const v4f*)(src + 4);
#pragma unroll
            for (int j = 0; j < 4; ++j)
                wq[j] = *(const v8s*)(wbase + (size_t)j * 64 * K2 + kn * BK);
        }
        __syncthreads();                              // tiles visible
#pragma unroll
        for (int ks = 0; ks < 2; ++ks) {
            v8s af[2], bf[4];
#pragma unroll
            for (int mt = 0; mt < 2; ++mt)            // A[m=l16][k=quad*8+j]
                af[mt] = *(const v8s*)(Xs + (wm * 32 + mt * 16 + l16) * XS + ks * 32 + quad * 8);
#pragma unroll
            for (int nt = 0; nt < 4; ++nt)            // B[k=quad*8+j][n=l16]
                bf[nt] = *(const v8s*)(Wts + (wn * 64 + nt * 16 + l16) * WS + ks * 32 + quad * 8);
#pragma unroll
            for (int mt = 0; mt < 2; ++mt)
#pragma unroll
                for (int nt = 0; nt < 4; ++nt)
                    acc[mt][nt] = __builtin_amdgcn_mfma_f32_16x16x32_bf16(
                        af[mt], bf[nt], acc[mt][nt], 0, 0, 0);
        }
    }

    // ---- epilogue: relu(acc + b1) * w2, reduce over n ----
    float b1v[4], w2v[4];
#pragma unroll
    for (int nt = 0; nt < 4; ++nt) {
        int n = wn * 64 + nt * 16 + l16;
        b1v[nt] = b1[n];
        w2v[nt] = w2[n];
    }
    const float b2v = b2[0];

#pragma unroll
    for (int mt = 0; mt < 2; ++mt) {
        float s[4] = {0.f, 0.f, 0.f, 0.f};
#pragma unroll
        for (int nt = 0; nt < 4; ++nt) {
#pragma unroll
            for (int j = 0; j < 4; ++j) {
                float h = acc[mt][nt][j] + b1v[nt];   // D row = quad*4+j, col = l16
                h = h > 0.f ? h : 0.f;
                s[j] += h * w2v[nt];
            }
        }
#pragma unroll
        for (int j = 0; j < 4; ++j) {
            float v = s[j];
            v += __shfl_xor(v, 1, 64);                // reduce 16 cols within quad
            v += __shfl_xor(v, 2, 64);
            v += __shfl_xor(v, 4, 64);
            v += __shfl_xor(v, 8, 64);
            if (l16 == 0)
                red[wn][wm * 32 + mt * 16 + quad * 4 + j] = v;
        }
    }
    __syncthreads();
    if (t < BM) {
        long e = e0 + t;
        if (e < E) {
            float v = red[0][t] + red[1][t] + red[2][t] + red[3][t] + b2v;
            out[e] = v;
        }
    }
}

extern "C" void kernel_launch(void* const* d_in, const int* in_sizes, int n_in,
                              void* d_out, int out_size, void* d_ws, size_t ws_size,
                              hipStream_t stream) {
    const float* user_emb  = (const float*)d_in[0];
    const float* movie_emb = (const float*)d_in[1];
    const int*   eli       = (const int*)d_in[2];
    const float* w1        = (const float*)d_in[3];
    const float* b1        = (const float*)d_in[4];
    const float* w2        = (const float*)d_in[5];
    const float* b2        = (const float*)d_in[6];
    float*       out       = (float*)d_out;

    const int E        = out_size;
    const int n_users  = in_sizes[0] / H;
    const int n_movies = in_sizes[1] / H;

    unsigned short* w1t = (unsigned short*)d_ws;      // 512*256*2 = 256 KiB scratch

    w1_transpose_kernel<<<dim3(16, 8), 256, 0, stream>>>(w1, w1t);
    const int nblocks = (E + BM - 1) / BM;
    edge_decoder_kernel<<<nblocks, 512, 0, stream>>>(
        user_emb, movie_emb, eli, w1t, b1, w2, b2, out, E, n_users, n_movies);
}

// Round 7
// 298.366 us; speedup vs baseline: 1.3468x; 1.2796x over previous
//
#include <hip/hip_runtime.h>
#include <hip/hip_bf16.h>

typedef __attribute__((ext_vector_type(8))) short v8s;   // 8 x bf16 (4 VGPRs)
typedef __attribute__((ext_vector_type(4))) float v4f;   // float4 / MFMA acc

constexpr int H  = 256;   // hidden channels
constexpr int K2 = 512;   // 2H
constexpr int XS = 72;    // padded LDS stride (bf16 elems)
constexpr int WS = 72;

__device__ inline unsigned short f2bf(float f) {         // fp32 -> bf16 bits, RNE
    unsigned int u = __builtin_bit_cast(unsigned int, f);
    u += 0x7FFFu + ((u >> 16) & 1u);
    return (unsigned short)(u >> 16);
}
__device__ inline float bf2f(unsigned short s) {
    return __builtin_bit_cast(float, (unsigned int)s << 16);
}

// ---- pre-kernel: W1 fp32 [512][256] (k-major) -> W1T bf16 [256][512] (n-major) ----
__global__ void w1_transpose_kernel(const float* __restrict__ w1,
                                    unsigned short* __restrict__ w1t) {
    __shared__ float tile[32][33];
    const int bk = blockIdx.x;            // 16 blocks over k
    const int bn = blockIdx.y;            // 8 blocks over n
    const int tx = threadIdx.x & 31;
    const int ty8 = threadIdx.x >> 5;     // 0..7
#pragma unroll
    for (int i = 0; i < 4; ++i) {
        int ty = i * 8 + ty8;
        tile[ty][tx] = w1[(size_t)(bk * 32 + ty) * H + bn * 32 + tx];
    }
    __syncthreads();
#pragma unroll
    for (int i = 0; i < 4; ++i) {
        int ty = i * 8 + ty8;
        w1t[(size_t)(bn * 32 + ty) * K2 + bk * 32 + tx] = f2bf(tile[tx][ty]);
    }
}

// ---- dense GEMM: out[m][n] = emb[m][0:256] @ W1T[n][kofs:kofs+256] (+bias), bf16 out ----
// block = 512 thr (8 waves), BM=128, BN=256, wave tile 64x64, BK=64, 4 K-tiles
__global__ __launch_bounds__(512) void emb_gemm_kernel(
    const float* __restrict__ emb,          // [M][256] fp32
    const unsigned short* __restrict__ w1t, // [256][512] bf16
    const float* __restrict__ bias,         // [256] or nullptr
    unsigned short* __restrict__ outp,      // [M][256] bf16
    const int M, const int kofs)
{
    __shared__ unsigned short Xs[128 * XS]; // 18432 B
    __shared__ unsigned short Wts[H * WS];  // 36864 B

    const int t    = threadIdx.x;
    const int wave = t >> 6;
    const int lane = t & 63;
    const int wm   = wave >> 2;   // 0..1
    const int wn   = wave & 3;    // 0..3
    const int quad = lane >> 4;
    const int l16  = lane & 15;

    const long m0 = (long)blockIdx.x * 128;

    // X staging: row xr=t>>2 (0..127), chunks xc & xc+4 (8 floats each)
    const int xr = t >> 2;
    const int xc = t & 3;
    long mr = m0 + xr; if (mr >= M) mr = M - 1;
    const float* arow = emb + (size_t)mr * H;

    // W staging: rows j*64+wr (j=0..3), chunk wc8 (8 bf16)
    const int wr  = t >> 3;
    const int wc8 = t & 7;

    v4f acc[4][4];
#pragma unroll
    for (int mt = 0; mt < 4; ++mt)
#pragma unroll
        for (int nt = 0; nt < 4; ++nt)
            acc[mt][nt] = (v4f){0.f, 0.f, 0.f, 0.f};

    for (int kt = 0; kt < 4; ++kt) {
        __syncthreads();
        // X: fp32 -> bf16 into LDS (two 8-elem chunks)
        {
            const float* s0 = arow + kt * 64 + xc * 8;
            v4f a0 = *(const v4f*)(s0);
            v4f a1 = *(const v4f*)(s0 + 4);
            v4f a2 = *(const v4f*)(s0 + 32);
            v4f a3 = *(const v4f*)(s0 + 36);
            v8s x0, x1;
#pragma unroll
            for (int i = 0; i < 4; ++i) { x0[i] = (short)f2bf(a0[i]); x0[4+i] = (short)f2bf(a1[i]); }
#pragma unroll
            for (int i = 0; i < 4; ++i) { x1[i] = (short)f2bf(a2[i]); x1[4+i] = (short)f2bf(a3[i]); }
            *(v8s*)(Xs + xr * XS + xc * 8)      = x0;
            *(v8s*)(Xs + xr * XS + xc * 8 + 32) = x1;
        }
        // W: bf16 global -> LDS
#pragma unroll
        for (int j = 0; j < 4; ++j) {
            v8s wv = *(const v8s*)(w1t + (size_t)(j * 64 + wr) * K2 + kofs + kt * 64 + wc8 * 8);
            *(v8s*)(Wts + (j * 64 + wr) * WS + wc8 * 8) = wv;
        }
        __syncthreads();
#pragma unroll
        for (int ks = 0; ks < 2; ++ks) {
            v8s af[4], bf[4];
#pragma unroll
            for (int mt = 0; mt < 4; ++mt)
                af[mt] = *(const v8s*)(Xs + (wm * 64 + mt * 16 + l16) * XS + ks * 32 + quad * 8);
#pragma unroll
            for (int nt = 0; nt < 4; ++nt)
                bf[nt] = *(const v8s*)(Wts + (wn * 64 + nt * 16 + l16) * WS + ks * 32 + quad * 8);
#pragma unroll
            for (int mt = 0; mt < 4; ++mt)
#pragma unroll
                for (int nt = 0; nt < 4; ++nt)
                    acc[mt][nt] = __builtin_amdgcn_mfma_f32_16x16x32_bf16(
                        af[mt], bf[nt], acc[mt][nt], 0, 0, 0);
        }
    }

    // epilogue: (+bias), bf16 store. D: col=l16, row=quad*4+j
    float bv[4];
#pragma unroll
    for (int nt = 0; nt < 4; ++nt)
        bv[nt] = bias ? bias[wn * 64 + nt * 16 + l16] : 0.f;

#pragma unroll
    for (int mt = 0; mt < 4; ++mt) {
#pragma unroll
        for (int j = 0; j < 4; ++j) {
            long m = m0 + wm * 64 + mt * 16 + quad * 4 + j;
            if (m < M) {
#pragma unroll
                for (int nt = 0; nt < 4; ++nt) {
                    int n = wn * 64 + nt * 16 + l16;
                    outp[(size_t)m * H + n] = f2bf(acc[mt][nt][j] + bv[nt]);
                }
            }
        }
    }
}

// ---- edge pass: out[e] = relu(P[u] + Q[m]) . w2 + b2 ----
// block 256 thr = 4 waves = 8 half-waves; each half-wave does 8 edges (64/block)
__global__ __launch_bounds__(256, 8) void edge_score_kernel(
    const unsigned short* __restrict__ P,   // [n_users][256] bf16 (b1 folded in)
    const unsigned short* __restrict__ Q,   // [n_movies][256] bf16
    const int* __restrict__ eli,            // [2][E] int32
    const float* __restrict__ w2,           // [256]
    const float* __restrict__ b2,           // [1]
    float* __restrict__ out,                // [E]
    const int E, const int n_users, const int n_movies)
{
    const int t   = threadIdx.x;
    const int hw  = t >> 5;        // half-wave id in block: 0..7
    const int l32 = t & 31;

    float w2v[8];
    {
        v4f a = *(const v4f*)(w2 + l32 * 8);
        v4f b = *(const v4f*)(w2 + l32 * 8 + 4);
#pragma unroll
        for (int i = 0; i < 4; ++i) { w2v[i] = a[i]; w2v[4 + i] = b[i]; }
    }
    const float b2v = b2[0];
    const long base = (long)blockIdx.x * 64;

#pragma unroll
    for (int i = 0; i < 8; ++i) {
        long e = base + i * 8 + hw;
        const bool valid = (e < E);
        long ec = valid ? e : 0;
        int u = eli[ec];
        int m = eli[(long)E + ec];
        u = u < 0 ? 0 : (u >= n_users  ? n_users  - 1 : u);
        m = m < 0 ? 0 : (m >= n_movies ? n_movies - 1 : m);
        v8s pv = *(const v8s*)(P + (size_t)u * H + l32 * 8);
        v8s qv = *(const v8s*)(Q + (size_t)m * H + l32 * 8);
        float s = 0.f;
#pragma unroll
        for (int j = 0; j < 8; ++j) {
            float h = bf2f((unsigned short)pv[j]) + bf2f((unsigned short)qv[j]);
            h = h > 0.f ? h : 0.f;
            s += h * w2v[j];
        }
        s += __shfl_xor(s, 1, 64);
        s += __shfl_xor(s, 2, 64);
        s += __shfl_xor(s, 4, 64);
        s += __shfl_xor(s, 8, 64);
        s += __shfl_xor(s, 16, 64);
        if (l32 == 0 && valid) out[e] = s + b2v;
    }
}

// ================= round-6 fallback (verified) — used if ws_size too small ==========
constexpr int BMF = 64;
__global__ __launch_bounds__(512, 4) void edge_decoder_kernel(
    const float* __restrict__ user_emb, const float* __restrict__ movie_emb,
    const int* __restrict__ eli, const unsigned short* __restrict__ w1t,
    const float* __restrict__ b1, const float* __restrict__ w2,
    const float* __restrict__ b2, float* __restrict__ out,
    const int E, const int n_users, const int n_movies)
{
    __shared__ unsigned short Xs[BMF * XS];
    __shared__ unsigned short Wts[H * WS];
    __shared__ float red[4][BMF];
    const int t = threadIdx.x, wave = t >> 6, lane = t & 63;
    const int wm = wave >> 2, wn = wave & 3, quad = lane >> 4, l16 = lane & 15;
    const long e0 = (long)blockIdx.x * BMF;
    const int xr = t >> 3, xc = t & 7;
    long eg = e0 + xr; if (eg >= E) eg = 0;
    int iu = eli[eg], im = eli[(long)E + eg];
    iu = iu < 0 ? 0 : (iu >= n_users ? n_users - 1 : iu);
    im = im < 0 ? 0 : (im >= n_movies ? n_movies - 1 : im);
    const float* urow = user_emb + (size_t)iu * H;
    const float* mrow = movie_emb + (size_t)im * H;
    const int wr = t >> 3, wc8 = t & 7;
    const unsigned short* wbase = w1t + (size_t)wr * K2 + wc8 * 8;
    v4f acc[2][4];
#pragma unroll
    for (int mt = 0; mt < 2; ++mt)
#pragma unroll
        for (int nt = 0; nt < 4; ++nt) acc[mt][nt] = (v4f){0.f,0.f,0.f,0.f};
    v4f xq0 = *(const v4f*)(urow + xc * 8);
    v4f xq1 = *(const v4f*)(urow + xc * 8 + 4);
    v8s wq[4];
#pragma unroll
    for (int j = 0; j < 4; ++j) wq[j] = *(const v8s*)(wbase + (size_t)j * 64 * K2);
    for (int kt = 0; kt < 8; ++kt) {
        __syncthreads();
        { v8s xv;
#pragma unroll
          for (int i = 0; i < 4; ++i) xv[i] = (short)f2bf(xq0[i]);
#pragma unroll
          for (int i = 0; i < 4; ++i) xv[4+i] = (short)f2bf(xq1[i]);
          *(v8s*)(Xs + xr * XS + xc * 8) = xv; }
#pragma unroll
        for (int j = 0; j < 4; ++j) *(v8s*)(Wts + (j * 64 + wr) * WS + wc8 * 8) = wq[j];
        if (kt < 7) {
            const int kn = kt + 1, koff = (kn * 64) & 255;
            const float* src = ((kn < 4) ? urow : mrow) + koff + xc * 8;
            xq0 = *(const v4f*)(src); xq1 = *(const v4f*)(src + 4);
#pragma unroll
            for (int j = 0; j < 4; ++j) wq[j] = *(const v8s*)(wbase + (size_t)j * 64 * K2 + kn * 64);
        }
        __syncthreads();
#pragma unroll
        for (int ks = 0; ks < 2; ++ks) {
            v8s af[2], bf[4];
#pragma unroll
            for (int mt = 0; mt < 2; ++mt)
                af[mt] = *(const v8s*)(Xs + (wm * 32 + mt * 16 + l16) * XS + ks * 32 + quad * 8);
#pragma unroll
            for (int nt = 0; nt < 4; ++nt)
                bf[nt] = *(const v8s*)(Wts + (wn * 64 + nt * 16 + l16) * WS + ks * 32 + quad * 8);
#pragma unroll
            for (int mt = 0; mt < 2; ++mt)
#pragma unroll
                for (int nt = 0; nt < 4; ++nt)
                    acc[mt][nt] = __builtin_amdgcn_mfma_f32_16x16x32_bf16(af[mt], bf[nt], acc[mt][nt], 0, 0, 0);
        }
    }
    float b1v[4], w2v[4];
#pragma unroll
    for (int nt = 0; nt < 4; ++nt) {
        int n = wn * 64 + nt * 16 + l16;
        b1v[nt] = b1[n]; w2v[nt] = w2[n];
    }
    const float b2v = b2[0];
#pragma unroll
    for (int mt = 0; mt < 2; ++mt) {
        float s[4] = {0.f,0.f,0.f,0.f};
#pragma unroll
        for (int nt = 0; nt < 4; ++nt)
#pragma unroll
            for (int j = 0; j < 4; ++j) {
                float h = acc[mt][nt][j] + b1v[nt];
                h = h > 0.f ? h : 0.f;
                s[j] += h * w2v[nt];
            }
#pragma unroll
        for (int j = 0; j < 4; ++j) {
            float v = s[j];
            v += __shfl_xor(v, 1, 64); v += __shfl_xor(v, 2, 64);
            v += __shfl_xor(v, 4, 64); v += __shfl_xor(v, 8, 64);
            if (l16 == 0) red[wn][wm * 32 + mt * 16 + quad * 4 + j] = v;
        }
    }
    __syncthreads();
    if (t < BMF) {
        long e = e0 + t;
        if (e < E) out[e] = red[0][t] + red[1][t] + red[2][t] + red[3][t] + b2v;
    }
}

extern "C" void kernel_launch(void* const* d_in, const int* in_sizes, int n_in,
                              void* d_out, int out_size, void* d_ws, size_t ws_size,
                              hipStream_t stream) {
    const float* user_emb  = (const float*)d_in[0];
    const float* movie_emb = (const float*)d_in[1];
    const int*   eli       = (const int*)d_in[2];
    const float* w1        = (const float*)d_in[3];
    const float* b1        = (const float*)d_in[4];
    const float* w2        = (const float*)d_in[5];
    const float* b2        = (const float*)d_in[6];
    float*       out       = (float*)d_out;

    const int E        = out_size;
    const int n_users  = in_sizes[0] / H;
    const int n_movies = in_sizes[1] / H;

    unsigned short* w1t = (unsigned short*)d_ws;                 // 256 KiB
    const size_t w1t_bytes = (size_t)K2 * H * 2;
    const size_t p_bytes   = (size_t)n_users  * H * 2;
    const size_t q_bytes   = (size_t)n_movies * H * 2;

    w1_transpose_kernel<<<dim3(16, 8), 256, 0, stream>>>(w1, w1t);

    if (ws_size >= w1t_bytes + p_bytes + q_bytes) {
        unsigned short* P = (unsigned short*)((char*)d_ws + w1t_bytes);
        unsigned short* Q = (unsigned short*)((char*)d_ws + w1t_bytes + p_bytes);
        emb_gemm_kernel<<<(n_users  + 127) / 128, 512, 0, stream>>>(
            user_emb,  w1t, b1,      P, n_users,  0);
        emb_gemm_kernel<<<(n_movies + 127) / 128, 512, 0, stream>>>(
            movie_emb, w1t, nullptr, Q, n_movies, 256);
        edge_score_kernel<<<(E + 63) / 64, 256, 0, stream>>>(
            P, Q, eli, w2, b2, out, E, n_users, n_movies);
    } else {
        edge_decoder_kernel<<<(E + BMF - 1) / BMF, 512, 0, stream>>>(
            user_emb, movie_emb, eli, w1t, b1, w2, b2, out, E, n_users, n_movies);
    }
}

// Round 8
// 286.495 us; speedup vs baseline: 1.4026x; 1.0414x over previous
//
#include <hip/hip_runtime.h>
#include <hip/hip_bf16.h>

typedef __attribute__((ext_vector_type(8))) short v8s;   // 8 x bf16 (4 VGPRs)
typedef __attribute__((ext_vector_type(4))) float v4f;   // float4 / MFMA acc

constexpr int H  = 256;   // hidden channels
constexpr int K2 = 512;   // 2H
constexpr int XS = 72;    // padded LDS stride (bf16 elems)
constexpr int WS = 72;

__device__ inline unsigned short f2bf(float f) {         // fp32 -> bf16 bits, RNE
    unsigned int u = __builtin_bit_cast(unsigned int, f);
    u += 0x7FFFu + ((u >> 16) & 1u);
    return (unsigned short)(u >> 16);
}
__device__ inline float bf2f(unsigned short s) {
    return __builtin_bit_cast(float, (unsigned int)s << 16);
}

// ---- pre-kernel: W1 fp32 [512][256] (k-major) -> W1T bf16 [256][512] (n-major) ----
__global__ void w1_transpose_kernel(const float* __restrict__ w1,
                                    unsigned short* __restrict__ w1t) {
    __shared__ float tile[32][33];
    const int bk = blockIdx.x;
    const int bn = blockIdx.y;
    const int tx = threadIdx.x & 31;
    const int ty8 = threadIdx.x >> 5;
#pragma unroll
    for (int i = 0; i < 4; ++i) {
        int ty = i * 8 + ty8;
        tile[ty][tx] = w1[(size_t)(bk * 32 + ty) * H + bn * 32 + tx];
    }
    __syncthreads();
#pragma unroll
    for (int i = 0; i < 4; ++i) {
        int ty = i * 8 + ty8;
        w1t[(size_t)(bn * 32 + ty) * K2 + bk * 32 + tx] = f2bf(tile[tx][ty]);
    }
}

// ---- fused dense GEMM over BOTH tables: P = user@W1[:256]+b1 ; Q = movie@W1[256:] ----
// BM=64 rows/block, BN=256 (full), 512 thr = 8 waves, wave tile 32x64, BK=64, 4 K-tiles.
// X (fp32 HBM) and W (bf16 L2) register-prefetched across K-tiles.
__global__ __launch_bounds__(512, 4) void emb_gemm_fused_kernel(
    const float* __restrict__ user_emb,
    const float* __restrict__ movie_emb,
    const unsigned short* __restrict__ w1t, // [256][512] bf16
    const float* __restrict__ b1,           // [256]
    unsigned short* __restrict__ P,         // [n_users][256] bf16
    unsigned short* __restrict__ Q,         // [n_movies][256] bf16
    const int n_users, const int n_movies, const int nbu)
{
    __shared__ unsigned short Xs[64 * XS];  //  9216 B
    __shared__ unsigned short Wts[H * WS];  // 36864 B

    const int  isMovie = (blockIdx.x >= nbu) ? 1 : 0;
    const float* emb  = isMovie ? movie_emb : user_emb;
    unsigned short* outp = isMovie ? Q : P;
    const int  M     = isMovie ? n_movies : n_users;
    const int  kofs  = isMovie ? 256 : 0;
    const long m0    = (long)(blockIdx.x - (isMovie ? nbu : 0)) * 64;

    const int t    = threadIdx.x;
    const int wave = t >> 6;
    const int lane = t & 63;
    const int wm   = wave >> 2;   // 0..1 : 32-row half
    const int wn   = wave & 3;    // 0..3 : 64-col slice
    const int quad = lane >> 4;
    const int l16  = lane & 15;

    // X staging: row xr=t>>3 (0..63), chunk xc=t&7 (8 floats)
    const int xr = t >> 3;
    const int xc = t & 7;
    long mr = m0 + xr; if (mr >= M) mr = M - 1;
    const float* arow = emb + (size_t)mr * H;

    // W staging: rows j*64+wr (j=0..3), chunk wc8
    const int wr  = t >> 3;
    const int wc8 = t & 7;
    const unsigned short* wbase = w1t + (size_t)wr * K2 + kofs + wc8 * 8;

    v4f acc[2][4];
#pragma unroll
    for (int mt = 0; mt < 2; ++mt)
#pragma unroll
        for (int nt = 0; nt < 4; ++nt)
            acc[mt][nt] = (v4f){0.f, 0.f, 0.f, 0.f};

    // prefetch K-tile 0
    v4f a0 = *(const v4f*)(arow + xc * 8);
    v4f a1 = *(const v4f*)(arow + xc * 8 + 4);
    v8s wq[4];
#pragma unroll
    for (int j = 0; j < 4; ++j)
        wq[j] = *(const v8s*)(wbase + (size_t)j * 64 * K2);

    for (int kt = 0; kt < 4; ++kt) {
        __syncthreads();
        {
            v8s xv;
#pragma unroll
            for (int i = 0; i < 4; ++i) { xv[i] = (short)f2bf(a0[i]); xv[4+i] = (short)f2bf(a1[i]); }
            *(v8s*)(Xs + xr * XS + xc * 8) = xv;
        }
#pragma unroll
        for (int j = 0; j < 4; ++j)
            *(v8s*)(Wts + (j * 64 + wr) * WS + wc8 * 8) = wq[j];
        if (kt < 3) {
            const int kn = kt + 1;
            a0 = *(const v4f*)(arow + kn * 64 + xc * 8);
            a1 = *(const v4f*)(arow + kn * 64 + xc * 8 + 4);
#pragma unroll
            for (int j = 0; j < 4; ++j)
                wq[j] = *(const v8s*)(wbase + (size_t)j * 64 * K2 + kn * 64);
        }
        __syncthreads();
#pragma unroll
        for (int ks = 0; ks < 2; ++ks) {
            v8s af[2], bf[4];
#pragma unroll
            for (int mt = 0; mt < 2; ++mt)
                af[mt] = *(const v8s*)(Xs + (wm * 32 + mt * 16 + l16) * XS + ks * 32 + quad * 8);
#pragma unroll
            for (int nt = 0; nt < 4; ++nt)
                bf[nt] = *(const v8s*)(Wts + (wn * 64 + nt * 16 + l16) * WS + ks * 32 + quad * 8);
#pragma unroll
            for (int mt = 0; mt < 2; ++mt)
#pragma unroll
                for (int nt = 0; nt < 4; ++nt)
                    acc[mt][nt] = __builtin_amdgcn_mfma_f32_16x16x32_bf16(
                        af[mt], bf[nt], acc[mt][nt], 0, 0, 0);
        }
    }

    // epilogue: (+b1 for user side), bf16 store. D: col=l16, row=quad*4+j
    float bv[4];
#pragma unroll
    for (int nt = 0; nt < 4; ++nt)
        bv[nt] = isMovie ? 0.f : b1[wn * 64 + nt * 16 + l16];

#pragma unroll
    for (int mt = 0; mt < 2; ++mt) {
#pragma unroll
        for (int j = 0; j < 4; ++j) {
            long m = m0 + wm * 32 + mt * 16 + quad * 4 + j;
            if (m < M) {
#pragma unroll
                for (int nt = 0; nt < 4; ++nt) {
                    int n = wn * 64 + nt * 16 + l16;
                    outp[(size_t)m * H + n] = f2bf(acc[mt][nt][j] + bv[nt]);
                }
            }
        }
    }
}

// ---- edge pass: out[e] = relu(P[u] + Q[m]) . w2 + b2 ----
// block 256 thr = 8 half-waves; each half-wave does 8 edges; row loads double-buffered
__global__ __launch_bounds__(256, 8) void edge_score_kernel(
    const unsigned short* __restrict__ P,
    const unsigned short* __restrict__ Q,
    const int* __restrict__ eli,
    const float* __restrict__ w2,
    const float* __restrict__ b2,
    float* __restrict__ out,
    const int E, const int n_users, const int n_movies)
{
    const int t   = threadIdx.x;
    const int hw  = t >> 5;        // 0..7
    const int l32 = t & 31;

    float w2v[8];
    {
        v4f a = *(const v4f*)(w2 + l32 * 8);
        v4f b = *(const v4f*)(w2 + l32 * 8 + 4);
#pragma unroll
        for (int i = 0; i < 4; ++i) { w2v[i] = a[i]; w2v[4 + i] = b[i]; }
    }
    const float b2v = b2[0];
    const long base = (long)blockIdx.x * 64;

    // preload all 16 indices (independent loads issue together)
    int us[8], ms[8];
#pragma unroll
    for (int i = 0; i < 8; ++i) {
        long e = base + i * 8 + hw;
        long ec = (e < E) ? e : 0;
        int u = eli[ec];
        int m = eli[(long)E + ec];
        us[i] = u < 0 ? 0 : (u >= n_users  ? n_users  - 1 : u);
        ms[i] = m < 0 ? 0 : (m >= n_movies ? n_movies - 1 : m);
    }

    v8s pv = *(const v8s*)(P + (size_t)us[0] * H + l32 * 8);
    v8s qv = *(const v8s*)(Q + (size_t)ms[0] * H + l32 * 8);

#pragma unroll
    for (int i = 0; i < 8; ++i) {
        v8s pn, qn;
        if (i < 7) {                                   // next rows issue before compute
            pn = *(const v8s*)(P + (size_t)us[i + 1] * H + l32 * 8);
            qn = *(const v8s*)(Q + (size_t)ms[i + 1] * H + l32 * 8);
        }
        float s = 0.f;
#pragma unroll
        for (int j = 0; j < 8; ++j) {
            float h = bf2f((unsigned short)pv[j]) + bf2f((unsigned short)qv[j]);
            h = h > 0.f ? h : 0.f;
            s += h * w2v[j];
        }
        s += __shfl_xor(s, 1, 64);
        s += __shfl_xor(s, 2, 64);
        s += __shfl_xor(s, 4, 64);
        s += __shfl_xor(s, 8, 64);
        s += __shfl_xor(s, 16, 64);
        long e = base + i * 8 + hw;
        if (l32 == 0 && e < E) out[e] = s + b2v;
        pv = pn; qv = qn;
    }
}

// ================= round-6 fallback (verified) — used if ws_size too small ==========
constexpr int BMF = 64;
__global__ __launch_bounds__(512, 4) void edge_decoder_kernel(
    const float* __restrict__ user_emb, const float* __restrict__ movie_emb,
    const int* __restrict__ eli, const unsigned short* __restrict__ w1t,
    const float* __restrict__ b1, const float* __restrict__ w2,
    const float* __restrict__ b2, float* __restrict__ out,
    const int E, const int n_users, const int n_movies)
{
    __shared__ unsigned short Xs[BMF * XS];
    __shared__ unsigned short Wts[H * WS];
    __shared__ float red[4][BMF];
    const int t = threadIdx.x, wave = t >> 6, lane = t & 63;
    const int wm = wave >> 2, wn = wave & 3, quad = lane >> 4, l16 = lane & 15;
    const long e0 = (long)blockIdx.x * BMF;
    const int xr = t >> 3, xc = t & 7;
    long eg = e0 + xr; if (eg >= E) eg = 0;
    int iu = eli[eg], im = eli[(long)E + eg];
    iu = iu < 0 ? 0 : (iu >= n_users ? n_users - 1 : iu);
    im = im < 0 ? 0 : (im >= n_movies ? n_movies - 1 : im);
    const float* urow = user_emb + (size_t)iu * H;
    const float* mrow = movie_emb + (size_t)im * H;
    const int wr = t >> 3, wc8 = t & 7;
    const unsigned short* wbase = w1t + (size_t)wr * K2 + wc8 * 8;
    v4f acc[2][4];
#pragma unroll
    for (int mt = 0; mt < 2; ++mt)
#pragma unroll
        for (int nt = 0; nt < 4; ++nt) acc[mt][nt] = (v4f){0.f,0.f,0.f,0.f};
    v4f xq0 = *(const v4f*)(urow + xc * 8);
    v4f xq1 = *(const v4f*)(urow + xc * 8 + 4);
    v8s wq[4];
#pragma unroll
    for (int j = 0; j < 4; ++j) wq[j] = *(const v8s*)(wbase + (size_t)j * 64 * K2);
    for (int kt = 0; kt < 8; ++kt) {
        __syncthreads();
        { v8s xv;
#pragma unroll
          for (int i = 0; i < 4; ++i) xv[i] = (short)f2bf(xq0[i]);
#pragma unroll
          for (int i = 0; i < 4; ++i) xv[4+i] = (short)f2bf(xq1[i]);
          *(v8s*)(Xs + xr * XS + xc * 8) = xv; }
#pragma unroll
        for (int j = 0; j < 4; ++j) *(v8s*)(Wts + (j * 64 + wr) * WS + wc8 * 8) = wq[j];
        if (kt < 7) {
            const int kn = kt + 1, koff = (kn * 64) & 255;
            const float* src = ((kn < 4) ? urow : mrow) + koff + xc * 8;
            xq0 = *(const v4f*)(src); xq1 = *(const v4f*)(src + 4);
#pragma unroll
            for (int j = 0; j < 4; ++j) wq[j] = *(const v8s*)(wbase + (size_t)j * 64 * K2 + kn * 64);
        }
        __syncthreads();
#pragma unroll
        for (int ks = 0; ks < 2; ++ks) {
            v8s af[2], bf[4];
#pragma unroll
            for (int mt = 0; mt < 2; ++mt)
                af[mt] = *(const v8s*)(Xs + (wm * 32 + mt * 16 + l16) * XS + ks * 32 + quad * 8);
#pragma unroll
            for (int nt = 0; nt < 4; ++nt)
                bf[nt] = *(const v8s*)(Wts + (wn * 64 + nt * 16 + l16) * WS + ks * 32 + quad * 8);
#pragma unroll
            for (int mt = 0; mt < 2; ++mt)
#pragma unroll
                for (int nt = 0; nt < 4; ++nt)
                    acc[mt][nt] = __builtin_amdgcn_mfma_f32_16x16x32_bf16(af[mt], bf[nt], acc[mt][nt], 0, 0, 0);
        }
    }
    float b1v[4], w2v[4];
#pragma unroll
    for (int nt = 0; nt < 4; ++nt) {
        int n = wn * 64 + nt * 16 + l16;
        b1v[nt] = b1[n]; w2v[nt] = w2[n];
    }
    const float b2v = b2[0];
#pragma unroll
    for (int mt = 0; mt < 2; ++mt) {
        float s[4] = {0.f,0.f,0.f,0.f};
#pragma unroll
        for (int nt = 0; nt < 4; ++nt)
#pragma unroll
            for (int j = 0; j < 4; ++j) {
                float h = acc[mt][nt][j] + b1v[nt];
                h = h > 0.f ? h : 0.f;
                s[j] += h * w2v[nt];
            }
#pragma unroll
        for (int j = 0; j < 4; ++j) {
            float v = s[j];
            v += __shfl_xor(v, 1, 64); v += __shfl_xor(v, 2, 64);
            v += __shfl_xor(v, 4, 64); v += __shfl_xor(v, 8, 64);
            if (l16 == 0) red[wn][wm * 32 + mt * 16 + quad * 4 + j] = v;
        }
    }
    __syncthreads();
    if (t < BMF) {
        long e = e0 + t;
        if (e < E) out[e] = red[0][t] + red[1][t] + red[2][t] + red[3][t] + b2v;
    }
}

extern "C" void kernel_launch(void* const* d_in, const int* in_sizes, int n_in,
                              void* d_out, int out_size, void* d_ws, size_t ws_size,
                              hipStream_t stream) {
    const float* user_emb  = (const float*)d_in[0];
    const float* movie_emb = (const float*)d_in[1];
    const int*   eli       = (const int*)d_in[2];
    const float* w1        = (const float*)d_in[3];
    const float* b1        = (const float*)d_in[4];
    const float* w2        = (const float*)d_in[5];
    const float* b2        = (const float*)d_in[6];
    float*       out       = (float*)d_out;

    const int E        = out_size;
    const int n_users  = in_sizes[0] / H;
    const int n_movies = in_sizes[1] / H;

    unsigned short* w1t = (unsigned short*)d_ws;                 // 256 KiB
    const size_t w1t_bytes = (size_t)K2 * H * 2;
    const size_t p_bytes   = (size_t)n_users  * H * 2;
    const size_t q_bytes   = (size_t)n_movies * H * 2;

    w1_transpose_kernel<<<dim3(16, 8), 256, 0, stream>>>(w1, w1t);

    if (ws_size >= w1t_bytes + p_bytes + q_bytes) {
        unsigned short* P = (unsigned short*)((char*)d_ws + w1t_bytes);
        unsigned short* Q = (unsigned short*)((char*)d_ws + w1t_bytes + p_bytes);
        const int nbu = (n_users  + 63) / 64;
        const int nbm = (n_movies + 63) / 64;
        emb_gemm_fused_kernel<<<nbu + nbm, 512, 0, stream>>>(
            user_emb, movie_emb, w1t, b1, P, Q, n_users, n_movies, nbu);
        edge_score_kernel<<<(E + 63) / 64, 256, 0, stream>>>(
            P, Q, eli, w2, b2, out, E, n_users, n_movies);
    } else {
        edge_decoder_kernel<<<(E + BMF - 1) / BMF, 512, 0, stream>>>(
            user_emb, movie_emb, eli, w1t, b1, w2, b2, out, E, n_users, n_movies);
    }
}